// Round 8
// baseline (181.690 us; speedup 1.0000x reference)
//
#include <hip/hip_runtime.h>
#include <math.h>

#define BB  4
#define NN  2000
#define TT  24
#define FIN 16
#define HH  128
#define EE  64000
#define CC  6
#define BN  (BB*NN)   // 8000

typedef _Float16 f16x8 __attribute__((ext_vector_type(8)));
typedef float f32x4 __attribute__((ext_vector_type(4)));

// ---------------- prep kernels ----------------
__global__ void fused_transpose_kernel(const float* __restrict__ gW1,
                                       const float* __restrict__ gW2,
                                       const float* __restrict__ cW1,
                                       float* __restrict__ o1, float* __restrict__ o2,
                                       float* __restrict__ o3) {
    int b = blockIdx.x;
    int tid = threadIdx.x;
    if (b < 64) {
        int idx = b * 256 + tid;                  // 128x128
        int r = idx >> 7, c = idx & 127;
        o1[c * 128 + r] = gW1[idx];
    } else if (b < 128) {
        int idx = (b - 64) * 256 + tid;
        int r = idx >> 7, c = idx & 127;
        o2[c * 128 + r] = gW2[idx];
    } else {
        int idx = (b - 128) * 256 + tid;          // 128x256
        int r = idx >> 8, c = idx & 255;
        o3[c * 128 + r] = cW1[idx];
    }
}

__global__ void cnt_kernel(const int* __restrict__ dst, int* __restrict__ cnt) {
    int e = blockIdx.x * 256 + threadIdx.x;
    if (e < EE) atomicAdd(&cnt[dst[e]], 1);
}

// scan + dis fused (single block)
__global__ __launch_bounds__(256) void scan_kernel(const int* __restrict__ cnt,
                                                   int* __restrict__ rowptr,
                                                   int* __restrict__ cursor,
                                                   float* __restrict__ dis) {
    __shared__ int part[256];
    int tid = threadIdx.x;
    int base = tid * 8;
    int loc[8]; int s = 0;
    #pragma unroll
    for (int u = 0; u < 8; ++u) {
        int v = (base + u < NN) ? cnt[base + u] : 0;
        loc[u] = s; s += v;
    }
    part[tid] = s;
    __syncthreads();
    #pragma unroll
    for (int off = 1; off < 256; off <<= 1) {
        int add = (tid >= off) ? part[tid - off] : 0;
        __syncthreads();
        part[tid] += add;
        __syncthreads();
    }
    int offset = (tid > 0) ? part[tid - 1] : 0;
    #pragma unroll
    for (int u = 0; u < 8; ++u) {
        int idx = base + u;
        if (idx < NN) {
            rowptr[idx] = offset + loc[u];
            cursor[idx] = offset + loc[u];
            dis[idx] = rsqrtf(fmaxf((float)cnt[idx], 1.0f));
        }
    }
    if (tid == 255) rowptr[NN] = part[255];
}

__global__ void csr_fill_kernel(const int* __restrict__ src, const int* __restrict__ dst,
                                const float* __restrict__ dis, int* __restrict__ cursor,
                                int* __restrict__ esrc, float* __restrict__ enorm) {
    int e = blockIdx.x * 256 + threadIdx.x;
    if (e < EE) {
        int d = dst[e], s = src[e];
        int pos = atomicAdd(&cursor[d], 1);
        esrc[pos] = s;
        enorm[pos] = dis[s] * dis[d];
    }
}

// ---------------- GRU via MFMA ----------------
// R6 was dependency-stall-bound (MfmaUtil 26%, 7200cyc/step vs ~1800 pipe-busy floor):
// 10-deep MFMA chains per gate, per-step global x load, nothing in barrier shadow.
// R7: (1) x staged ONCE in LDS as prepacked fp16 hi/lo fragments; (2) accumulators
// split by kf parity -> 4-deep in-loop chains; (3) next step's ih MFMAs issued in the
// barrier shadow (depend only on read-only X). Structure otherwise as R6: 500 blocks,
// 512 thr = 8 waves, 16 seqs/block; wave w owns units [w*16,w*16+16) of all 3 gates;
// gate math in registers; H dbuf fp16 hi/lo in LDS; 1 barrier/step.
// NO launch_bounds min-occupancy arg (R2/R3: forced VGPR caps -> GB-scale spill).
#define HP2 136

__global__ __launch_bounds__(512) void gru_mfma_kernel(
    const float* __restrict__ x,       // [BN][TT][FIN]
    const float* __restrict__ W_hh,    // [384][128]
    const float* __restrict__ W_ih,    // [384][16]
    const float* __restrict__ b_ih, const float* __restrict__ b_hh,
    float* __restrict__ temporal)      // [BN][HH]
{
    const int tid  = threadIdx.x;
    const int lane = tid & 63;
    const int w    = tid >> 6;
    const int l15  = lane & 15;
    const int lg   = lane >> 4;
    const int m0   = blockIdx.x * 16;
    const int u    = w * 16 + l15;

    __shared__ __align__(16) unsigned short Hhi[2][16][HP2];   // 8.5 KB
    __shared__ __align__(16) unsigned short Hlo[2][16][HP2];   // 8.5 KB
    __shared__ __align__(16) unsigned short Xhi[TT][16][FIN];  // 12 KB
    __shared__ __align__(16) unsigned short Xlo[TT][16][FIN];  // 12 KB

    // ---- B-fragments: W_hh (fp16 single), 3 gates x 4 kf ----
    f16x8 Bh[3][4];
    #pragma unroll
    for (int g = 0; g < 3; ++g) {
        const int col = g * 128 + u;
        #pragma unroll
        for (int kf = 0; kf < 4; ++kf) {
            const float* wp = W_hh + col * 128 + kf * 32 + lg * 8;
            float4 c0 = *(const float4*)wp;
            float4 c1 = *(const float4*)(wp + 4);
            f16x8 b;
            b[0] = (_Float16)c0.x; b[1] = (_Float16)c0.y;
            b[2] = (_Float16)c0.z; b[3] = (_Float16)c0.w;
            b[4] = (_Float16)c1.x; b[5] = (_Float16)c1.y;
            b[6] = (_Float16)c1.z; b[7] = (_Float16)c1.w;
            Bh[g][kf] = b;
        }
    }
    // ---- B-fragments: W_ih + bias at k==16 ----
    f16x8 Bi[3];
    #pragma unroll
    for (int g = 0; g < 3; ++g) {
        const int col = g * 128 + u;
        f16x8 b;
        #pragma unroll
        for (int i = 0; i < 8; ++i) b[i] = (_Float16)0.0f;
        if (lg < 2) {
            const float* wp = W_ih + col * 16 + lg * 8;
            float4 c0 = *(const float4*)wp;
            float4 c1 = *(const float4*)(wp + 4);
            b[0] = (_Float16)c0.x; b[1] = (_Float16)c0.y;
            b[2] = (_Float16)c0.z; b[3] = (_Float16)c0.w;
            b[4] = (_Float16)c1.x; b[5] = (_Float16)c1.y;
            b[6] = (_Float16)c1.z; b[7] = (_Float16)c1.w;
        } else if (lg == 2) {
            float bias = b_ih[col] + ((g < 2) ? b_hh[col] : 0.0f);
            b[0] = (_Float16)bias;   // k == 16
        }
        Bi[g] = b;
    }

    const float bhn = b_hh[256 + u];
    float hprev[4] = {0.0f, 0.0f, 0.0f, 0.0f};

    // ---- stage X once: fp32 -> fp16 hi/lo, [t][seq][f] ----
    for (int i = tid; i < TT * 16 * FIN; i += 512) {
        int t   = i >> 8;           // /256
        int rem = i & 255;
        int seq = rem >> 4;
        int f   = rem & 15;
        float v = x[(size_t)(m0 + seq) * (TT * FIN) + t * FIN + f];
        _Float16 hb = (_Float16)v;
        _Float16 lb = (_Float16)(v - (float)hb);
        Xhi[t][seq][f] = *(unsigned short*)&hb;
        Xlo[t][seq][f] = *(unsigned short*)&lb;
    }
    for (int i = tid; i < 16 * HP2; i += 512) {
        (&Hhi[0][0][0])[i] = 0;
        (&Hlo[0][0][0])[i] = 0;
    }
    __syncthreads();

    const f32x4 Z4 = (f32x4){0.f, 0.f, 0.f, 0.f};
    f32x4 aR0, aR1, aZ0, aZ1, aH0, aH1, aI;

    // ih for step tt into fresh accumulators (runs in barrier shadow for tt>0)
#define IH_SHADOW(tt) do { \
        f16x8 axh, axl; \
        _Float16 zz = (_Float16)0.0f; \
        axh = (f16x8){zz,zz,zz,zz,zz,zz,zz,zz}; \
        axl = axh; \
        if (lg < 2) { \
            axh = *(const f16x8*)&Xhi[tt][l15][lg * 8]; \
            axl = *(const f16x8*)&Xlo[tt][l15][lg * 8]; \
        } else if (lg == 2) { \
            axh[0] = (_Float16)1.0f; \
        } \
        aR0 = __builtin_amdgcn_mfma_f32_16x16x32_f16(axh, Bi[0], Z4, 0, 0, 0); \
        aR1 = __builtin_amdgcn_mfma_f32_16x16x32_f16(axl, Bi[0], Z4, 0, 0, 0); \
        aZ0 = __builtin_amdgcn_mfma_f32_16x16x32_f16(axh, Bi[1], Z4, 0, 0, 0); \
        aZ1 = __builtin_amdgcn_mfma_f32_16x16x32_f16(axl, Bi[1], Z4, 0, 0, 0); \
        aI  = __builtin_amdgcn_mfma_f32_16x16x32_f16(axh, Bi[2], Z4, 0, 0, 0); \
        aI  = __builtin_amdgcn_mfma_f32_16x16x32_f16(axl, Bi[2], aI, 0, 0, 0); \
        aH0 = Z4; aH1 = Z4; \
    } while (0)

    IH_SHADOW(0);

    for (int t = 0; t < TT; ++t) {
        const int rb = t & 1, wb = rb ^ 1;

        // ---- hh MFMAs: kf parity split -> two 4-deep chains per gate ----
        #pragma unroll
        for (int kf = 0; kf < 4; ++kf) {
            const int ko = kf * 32 + lg * 8;
            f16x8 ahh = *(const f16x8*)&Hhi[rb][l15][ko];
            f16x8 ahl = *(const f16x8*)&Hlo[rb][l15][ko];
            if ((kf & 1) == 0) {
                aR0 = __builtin_amdgcn_mfma_f32_16x16x32_f16(ahh, Bh[0][kf], aR0, 0, 0, 0);
                aR0 = __builtin_amdgcn_mfma_f32_16x16x32_f16(ahl, Bh[0][kf], aR0, 0, 0, 0);
                aZ0 = __builtin_amdgcn_mfma_f32_16x16x32_f16(ahh, Bh[1][kf], aZ0, 0, 0, 0);
                aZ0 = __builtin_amdgcn_mfma_f32_16x16x32_f16(ahl, Bh[1][kf], aZ0, 0, 0, 0);
                aH0 = __builtin_amdgcn_mfma_f32_16x16x32_f16(ahh, Bh[2][kf], aH0, 0, 0, 0);
                aH0 = __builtin_amdgcn_mfma_f32_16x16x32_f16(ahl, Bh[2][kf], aH0, 0, 0, 0);
            } else {
                aR1 = __builtin_amdgcn_mfma_f32_16x16x32_f16(ahh, Bh[0][kf], aR1, 0, 0, 0);
                aR1 = __builtin_amdgcn_mfma_f32_16x16x32_f16(ahl, Bh[0][kf], aR1, 0, 0, 0);
                aZ1 = __builtin_amdgcn_mfma_f32_16x16x32_f16(ahh, Bh[1][kf], aZ1, 0, 0, 0);
                aZ1 = __builtin_amdgcn_mfma_f32_16x16x32_f16(ahl, Bh[1][kf], aZ1, 0, 0, 0);
                aH1 = __builtin_amdgcn_mfma_f32_16x16x32_f16(ahh, Bh[2][kf], aH1, 0, 0, 0);
                aH1 = __builtin_amdgcn_mfma_f32_16x16x32_f16(ahl, Bh[2][kf], aH1, 0, 0, 0);
            }
        }

        f32x4 aR = aR0 + aR1;
        f32x4 aZ = aZ0 + aZ1;
        f32x4 aH = aH0 + aH1;
        f32x4 aIv = aI;

        // ---- gate math in registers (clamp-free tanh) ----
        #pragma unroll
        for (int p = 0; p < 4; ++p) {
            float r = __builtin_amdgcn_rcpf(1.0f + __expf(-aR[p]));
            float z = __builtin_amdgcn_rcpf(1.0f + __expf(-aZ[p]));
            float pre = fmaf(r, aH[p] + bhn, aIv[p]);
            float e2 = __expf(2.0f * pre);
            float n = fmaf(-2.0f, __builtin_amdgcn_rcpf(e2 + 1.0f), 1.0f);
            float h = fmaf(z, hprev[p] - n, n);
            hprev[p] = h;
            _Float16 hb = (_Float16)h;
            _Float16 lb = (_Float16)(h - (float)hb);
            const int seq = lg * 4 + p;
            Hhi[wb][seq][u] = *(unsigned short*)&hb;
            Hlo[wb][seq][u] = *(unsigned short*)&lb;
        }

        // ---- next step's ih in the barrier shadow (X is read-only) ----
        if (t + 1 < TT) IH_SHADOW(t + 1);
        __syncthreads();
    }
#undef IH_SHADOW

    #pragma unroll
    for (int p = 0; p < 4; ++p)
        temporal[(size_t)(m0 + lg * 4 + p) * HH + u] = hprev[p];
}

// ---------------- fused GCN layer: gather + linear + LayerNorm + ReLU ----------------
// 256 thr: edge-gather split across two thread-halves (halves the serial latency chain
// of the avg-degree-32 loop); GEMV 2 batches per half; LN reduced within each half.
__global__ __launch_bounds__(256) void gcn_kernel(
    const float* __restrict__ xin,     // [BB][NN][HH]
    const int* __restrict__ rowptr,    // [NN+1]
    const int* __restrict__ esrc,      // edges sorted by dst
    const float* __restrict__ enorm,
    const float* __restrict__ Wt,      // [HH][HH]  Wt[k][j] = W[j][k]
    const float* __restrict__ bias,
    const float* __restrict__ gma, const float* __restrict__ bta,
    float* __restrict__ out)           // [BB][NN][HH]
{
    const int n = blockIdx.x;
    const int tid = threadIdx.x;
    const int j = tid & 127;
    const int half = tid >> 7;
    const int beg = rowptr[n], end = rowptr[n + 1];
    const int len = end - beg;
    const int mid = beg + ((len + 1) >> 1);
    int e        = half ? mid : beg;
    const int e1 = half ? end : mid;

    float a0 = 0.f, a1 = 0.f, a2 = 0.f, a3 = 0.f;
    for (; e + 1 < e1; e += 2) {
        int   s0 = esrc[e],   s1 = esrc[e + 1];
        float m0 = enorm[e],  m1 = enorm[e + 1];
        const float* p0 = xin + (size_t)s0 * HH + j;
        const float* p1 = xin + (size_t)s1 * HH + j;
        float v00 = p0[0], v01 = p0[NN*HH], v02 = p0[2*NN*HH], v03 = p0[3*NN*HH];
        float v10 = p1[0], v11 = p1[NN*HH], v12 = p1[2*NN*HH], v13 = p1[3*NN*HH];
        a0 = fmaf(m0, v00, a0); a1 = fmaf(m0, v01, a1);
        a2 = fmaf(m0, v02, a2); a3 = fmaf(m0, v03, a3);
        a0 = fmaf(m1, v10, a0); a1 = fmaf(m1, v11, a1);
        a2 = fmaf(m1, v12, a2); a3 = fmaf(m1, v13, a3);
    }
    if (e < e1) {
        int s0 = esrc[e]; float m0 = enorm[e];
        const float* p0 = xin + (size_t)s0 * HH + j;
        a0 = fmaf(m0, p0[0],       a0); a1 = fmaf(m0, p0[NN*HH],   a1);
        a2 = fmaf(m0, p0[2*NN*HH], a2); a3 = fmaf(m0, p0[3*NN*HH], a3);
    }

    __shared__ __align__(16) float agg[BB][HH];
    __shared__ __align__(16) float pagg[BB][HH];
    if (half) {
        pagg[0][j] = a0; pagg[1][j] = a1; pagg[2][j] = a2; pagg[3][j] = a3;
    }
    __syncthreads();
    if (!half) {
        agg[0][j] = a0 + pagg[0][j]; agg[1][j] = a1 + pagg[1][j];
        agg[2][j] = a2 + pagg[2][j]; agg[3][j] = a3 + pagg[3][j];
    }
    __syncthreads();

    const float bj = bias[j];
    const int b0 = half * 2, b1 = half * 2 + 1;
    float c0 = bj, c1 = bj;
    #pragma unroll 4
    for (int k = 0; k < HH; ++k) {
        float wv = Wt[k * HH + j];
        c0 = fmaf(wv, agg[b0][k], c0);
        c1 = fmaf(wv, agg[b1][k], c1);
    }

    const int lane = tid & 63, wv_ = (tid >> 6) & 1;
    __shared__ float red[2][2][2][2];   // [half][wave][q][{s1,s2}]
    {
        float s1 = c0, s2 = c0 * c0;
        for (int off = 32; off >= 1; off >>= 1) { s1 += __shfl_down(s1, off); s2 += __shfl_down(s2, off); }
        if (lane == 0) { red[half][wv_][0][0] = s1; red[half][wv_][0][1] = s2; }
        s1 = c1; s2 = c1 * c1;
        for (int off = 32; off >= 1; off >>= 1) { s1 += __shfl_down(s1, off); s2 += __shfl_down(s2, off); }
        if (lane == 0) { red[half][wv_][1][0] = s1; red[half][wv_][1][1] = s2; }
    }
    __syncthreads();

    const float gj = gma[j], btj = bta[j];
    #pragma unroll
    for (int q = 0; q < 2; ++q) {
        float cv = q ? c1 : c0;
        float s1 = red[half][0][q][0] + red[half][1][q][0];
        float s2 = red[half][0][q][1] + red[half][1][q][1];
        float mu = s1 * (1.0f / HH);
        float var = s2 * (1.0f / HH) - mu * mu;
        float y = (cv - mu) * rsqrtf(var + 1e-5f) * gj + btj;
        out[((size_t)(half * 2 + q) * NN + n) * HH + j] = fmaxf(y, 0.0f);
    }
}

// ---------------- classifier (fused 2-layer MLP) ----------------
__global__ __launch_bounds__(128) void classifier_kernel(
    const float* __restrict__ tin,   // temporal [BN][HH]
    const float* __restrict__ sin_,  // spatial  [BN][HH]
    const float* __restrict__ Wt1,   // [2*HH][HH]
    const float* __restrict__ b1,
    const float* __restrict__ W2,    // [CC][HH]
    const float* __restrict__ b2,
    float* __restrict__ out)         // [BN][CC]
{
    const int j = threadIdx.x;
    const int r0 = blockIdx.x * 8;
    __shared__ __align__(16) float tb[HH][8];
    __shared__ __align__(16) float sb[HH][8];
    __shared__ __align__(16) float h1[HH][8];
    for (int i = j; i < 8 * HH; i += 128) {
        int r = i >> 7, k = i & 127;
        tb[k][r] = tin [(size_t)(r0 + r) * HH + k];
        sb[k][r] = sin_[(size_t)(r0 + r) * HH + k];
    }
    __syncthreads();

    float acc[8];
    float bj = b1[j];
    #pragma unroll
    for (int r = 0; r < 8; ++r) acc[r] = bj;
    #pragma unroll 2
    for (int k = 0; k < HH; ++k) {
        float w = Wt1[k * HH + j];
        float4 a  = *(const float4*)&tb[k][0];
        float4 b4 = *(const float4*)&tb[k][4];
        acc[0] = fmaf(w, a.x,  acc[0]); acc[1] = fmaf(w, a.y,  acc[1]);
        acc[2] = fmaf(w, a.z,  acc[2]); acc[3] = fmaf(w, a.w,  acc[3]);
        acc[4] = fmaf(w, b4.x, acc[4]); acc[5] = fmaf(w, b4.y, acc[5]);
        acc[6] = fmaf(w, b4.z, acc[6]); acc[7] = fmaf(w, b4.w, acc[7]);
    }
    #pragma unroll 2
    for (int k = 0; k < HH; ++k) {
        float w = Wt1[(HH + k) * HH + j];
        float4 a  = *(const float4*)&sb[k][0];
        float4 b4 = *(const float4*)&sb[k][4];
        acc[0] = fmaf(w, a.x,  acc[0]); acc[1] = fmaf(w, a.y,  acc[1]);
        acc[2] = fmaf(w, a.z,  acc[2]); acc[3] = fmaf(w, a.w,  acc[3]);
        acc[4] = fmaf(w, b4.x, acc[4]); acc[5] = fmaf(w, b4.y, acc[5]);
        acc[6] = fmaf(w, b4.z, acc[6]); acc[7] = fmaf(w, b4.w, acc[7]);
    }
    #pragma unroll
    for (int r = 0; r < 8; ++r) h1[j][r] = fmaxf(acc[r], 0.0f);
    __syncthreads();

    if (j < 8 * CC) {
        int r = j / CC, c = j - r * CC;
        float a = b2[c];
        for (int k = 0; k < HH; ++k) a = fmaf(W2[c * HH + k], h1[k][r], a);
        out[(size_t)(r0 + r) * CC + c] = a;
    }
}

// ---------------- launch ----------------
extern "C" void kernel_launch(void* const* d_in, const int* in_sizes, int n_in,
                              void* d_out, int out_size, void* d_ws, size_t ws_size,
                              hipStream_t stream) {
    const float* x    = (const float*)d_in[0];
    const int*   ei   = (const int*)  d_in[1];
    const float* W_ih = (const float*)d_in[2];
    const float* W_hh = (const float*)d_in[3];
    const float* b_ih = (const float*)d_in[4];
    const float* b_hh = (const float*)d_in[5];
    const float* gW1  = (const float*)d_in[6];
    const float* gb1  = (const float*)d_in[7];
    const float* gW2  = (const float*)d_in[8];
    const float* gb2  = (const float*)d_in[9];
    const float* lg1  = (const float*)d_in[10];
    const float* lb1  = (const float*)d_in[11];
    const float* lg2  = (const float*)d_in[12];
    const float* lb2  = (const float*)d_in[13];
    const float* cW1  = (const float*)d_in[14];
    const float* cb1  = (const float*)d_in[15];
    const float* cW2  = (const float*)d_in[16];
    const float* cb2  = (const float*)d_in[17];
    float* out = (float*)d_out;

    float* ws = (float*)d_ws;
    float* Wt_g1 = ws;  ws += 128 * 128;
    float* Wt_g2 = ws;  ws += 128 * 128;
    float* Wt_c1 = ws;  ws += 256 * 128;
    float* dis   = ws;  ws += 2048;
    float* enorm = ws;  ws += EE;
    float* temporal = ws; ws += (size_t)BN * HH;
    float* sA    = ws;  ws += (size_t)BN * HH;
    float* sB    = ws;  ws += (size_t)BN * HH;
    int* ip      = (int*)ws;
    int* cnt     = ip;  ip += 2048;
    int* rowptr  = ip;  ip += 2080;
    int* cursor  = ip;  ip += 2048;
    int* esrc    = ip;  ip += EE;

    const int* srcp = ei;
    const int* dstp = ei + EE;

    hipMemsetAsync(cnt, 0, 2048 * sizeof(int), stream);

    fused_transpose_kernel<<<256, 256, 0, stream>>>(gW1, gW2, cW1, Wt_g1, Wt_g2, Wt_c1);

    cnt_kernel<<<250, 256, 0, stream>>>(dstp, cnt);
    scan_kernel<<<1, 256, 0, stream>>>(cnt, rowptr, cursor, dis);
    csr_fill_kernel<<<250, 256, 0, stream>>>(srcp, dstp, dis, cursor, esrc, enorm);

    gru_mfma_kernel<<<BN / 16, 512, 0, stream>>>(x, W_hh, W_ih, b_ih, b_hh, temporal);

    gcn_kernel<<<NN, 256, 0, stream>>>(temporal, rowptr, esrc, enorm, Wt_g1, gb1, lg1, lb1, sA);
    gcn_kernel<<<NN, 256, 0, stream>>>(sA, rowptr, esrc, enorm, Wt_g2, gb2, lg2, lb2, sB);

    classifier_kernel<<<BN / 8, 128, 0, stream>>>(temporal, sB, Wt_c1, cb1, cW2, cb2, out);
}